// Round 11
// baseline (352.347 us; speedup 1.0000x reference)
//
#include <hip/hip_runtime.h>
#include <cstdint>

#define N_ANCH 8400
#define WMAX   132          // ceil(8400/64)
#define NB     (WMAX * 64)  // padded box slots: 8448

__device__ __forceinline__ uint64_t readlane64(uint64_t v, int lane) {
  unsigned lo = (unsigned)__builtin_amdgcn_readlane((int)(unsigned)(v & 0xffffffffull), lane);
  unsigned hi = (unsigned)__builtin_amdgcn_readlane((int)(unsigned)(v >> 32), lane);
  return ((uint64_t)hi << 32) | lo;
}
__device__ __forceinline__ uint64_t shflxor64(uint64_t v, int m) {
  int lo = __shfl_xor((int)(unsigned)(v & 0xffffffffull), m, 64);
  int hi = __shfl_xor((int)(unsigned)(v >> 32), m, 64);
  return ((uint64_t)(unsigned)hi << 32) | (unsigned)lo;
}

// Kernel A: exact stable rank (descending score, invalid -> -inf, ties by index),
// scatter boxes/scores into sorted order, count valid. (verified)
__global__ __launch_bounds__(256) void k_rank(const float* __restrict__ in,
                                              float* __restrict__ scores_s,
                                              float4* __restrict__ boxes_s,
                                              unsigned* __restrict__ nvp) {
  __shared__ alignas(16) float sc[N_ANCH];
  __shared__ int part[256];
  const int tid = threadIdx.x;
  const float* srow = in + 4 * N_ANCH;
  for (int j = tid; j < N_ANCH; j += 256) sc[j] = srow[j];
  __syncthreads();
  const int il = tid & 63, q = tid >> 6;
  const int i = blockIdx.x * 64 + il;
  const float si = (i < N_ANCH) ? sc[i] : 0.0f;
  const bool valid = si > 0.5f;
  const float key = valid ? si : -INFINITY;
  int cnt = 0;
  const float4* sc4 = (const float4*)sc;
  const int jb = q * (N_ANCH / 4);
  for (int jj = 0; jj < (N_ANCH / 16); ++jj) {
    float4 v = sc4[q * (N_ANCH / 16) + jj];
    int j0 = jb + jj * 4;
    float k0 = (v.x > 0.5f) ? v.x : -INFINITY;
    float k1 = (v.y > 0.5f) ? v.y : -INFINITY;
    float k2 = (v.z > 0.5f) ? v.z : -INFINITY;
    float k3 = (v.w > 0.5f) ? v.w : -INFINITY;
    cnt += (k0 > key) || (k0 == key && (j0 + 0) < i);
    cnt += (k1 > key) || (k1 == key && (j0 + 1) < i);
    cnt += (k2 > key) || (k2 == key && (j0 + 2) < i);
    cnt += (k3 > key) || (k3 == key && (j0 + 3) < i);
  }
  part[tid] = cnt;
  __syncthreads();
  if (q == 0 && i < N_ANCH) {
    int r = part[il] + part[64 + il] + part[128 + il] + part[192 + il];
    float cx = in[0 * N_ANCH + i], cy = in[1 * N_ANCH + i];
    float w  = in[2 * N_ANCH + i], h  = in[3 * N_ANCH + i];
    float x1 = cx - w * 0.5f, y1 = cy - h * 0.5f;
    float x2 = cx + w * 0.5f, y2 = cy + h * 0.5f;
    boxes_s[r] = make_float4(x1, y1, x2, y2);
    scores_s[r] = valid ? si : 0.0f;
    if (valid) atomicAdd(nvp, 1u);
  }
}

// Kernel B: sup matrix, row-major, stride Wp = (W+3)&~3, UPPER TRIANGLE ONLY
// (w >= rowblock; scan never reads below-diagonal words). Exact IoU path.
__global__ __launch_bounds__(256) void k_sup(const float4* __restrict__ boxes_s,
                                             const unsigned* __restrict__ nvp,
                                             unsigned long long* __restrict__ sup) {
  const int nv = (int)*nvp;
  const int W = (nv + 63) >> 6;
  const int Wp = (W + 3) & ~3;
  const int w = blockIdx.x;
  if (w >= W) return;
  if (w + 1 < (int)(blockIdx.y * 256) >> 6) return;   // whole block in lower triangle
  __shared__ float bx1[64], by1[64], bx2[64], by2[64], bar[64];
  const int tid = threadIdx.x;
  if (tid < 64) {
    int j = w * 64 + tid;
    float4 b = (j < N_ANCH) ? boxes_s[j] : make_float4(0.f, 0.f, 0.f, 0.f);
    bx1[tid] = b.x; by1[tid] = b.y; bx2[tid] = b.z; by2[tid] = b.w;
    bar[tid] = (b.z - b.x) * (b.w - b.y);
  }
  __syncthreads();
  const int i = blockIdx.y * 256 + tid;
  if (i >= nv) return;
  if (w < (i >> 6)) return;                            // lower triangle: never read
  float4 bi = boxes_s[i];
  float ai = (bi.z - bi.x) * (bi.w - bi.y);
  const int jmax = nv - w * 64;
  uint64_t bits = 0;
  #pragma unroll 8
  for (int l = 0; l < 64; ++l) {
    float lx = fmaxf(bi.x, bx1[l]);
    float ly = fmaxf(bi.y, by1[l]);
    float rx = fminf(bi.z, bx2[l]);
    float ry = fminf(bi.w, by2[l]);
    float dx = fmaxf(rx - lx, 0.0f);
    float dy = fmaxf(ry - ly, 0.0f);
    float inter = dx * dy;
    asm volatile("" : "+v"(inter));           // block fma-contraction into union
    float uni = (ai + bar[l]) - inter;        // reference op order
    float iou = inter / uni;                  // IEEE f32 div, matches numpy
    bits |= ((uint64_t)((l < jmax) && (iou > 0.5f))) << l;
  }
  sup[(size_t)i * Wp + w] = bits;
}

// Kernel C: SINGLE-WAVE lazy-evaluation scan. No apply phase, no prefetch
// state, no barriers. Per block k: ext-suppression word = OR over kept rows'
// sup[row][k] (per-lane gather of the LDS kept-offset list + shfl-OR reduce),
// then the proven serial diag resolve; kept rows appended to the LDS list.
// Final keep words stored to ws for the parallel k_out.
__global__ __launch_bounds__(64) void k_scan(const unsigned long long* __restrict__ sup_,
                                             const unsigned* __restrict__ nvp,
                                             unsigned long long* __restrict__ keepw_g) {
  __shared__ uint32_t kept_off[NB];   // byte offsets: row * Wp * 8
  const uint64_t* sup = (const uint64_t*)sup_;
  const uint8_t* supb = (const uint8_t*)sup_;
  const int lane = threadIdx.x;
  const int nv = (int)*nvp;
  const int W  = (nv + 63) >> 6;
  const int Wp = (W + 3) & ~3;
  kept_off[lane] = 0;                 // safe clamp target

  int nkept = 0;
  uint64_t dw = 0, dwn = 0;
  if (W > 0) dw = sup[(size_t)lane * Wp];          // diag word of block 0

  for (int k = 0; k < W; ++k) {
    // prefetch next block's diag (used next iteration -> latency hidden)
    dwn = (k + 1 < W) ? sup[((size_t)(k + 1) * 64 + lane) * Wp + (k + 1)] : 0ull;

    // ---- lazy external suppression: OR of kept rows' word k ----
    uint64_t acc = 0;
    for (int t = 0; t < nkept; t += 64) {
      int j = t + lane;
      if (j < nkept) {
        uint32_t off = kept_off[j];
        acc |= *(const uint64_t*)(supb + off + (size_t)k * 8);
      }
    }
    acc |= shflxor64(acc, 1);  acc |= shflxor64(acc, 2);  acc |= shflxor64(acc, 4);
    acc |= shflxor64(acc, 8);  acc |= shflxor64(acc, 16); acc |= shflxor64(acc, 32);

    // ---- candidates of block k ----
    const int remv = nv - k * 64;
    uint64_t word = (remv >= 64) ? ~0ull : ((1ull << remv) - 1ull);
    uint64_t bk = word & ~acc;

    // ---- serial diag resolve (proven chain) ----
    uint64_t cand = bk;
    while (cand) {
      int r = (int)__builtin_ctzll(cand);
      uint64_t sr = readlane64(dw, r);
      uint64_t m = sr & ~((2ull << r) - 1ull);   // cols strictly > r
      cand &= ~(1ull << r);
      cand &= ~m;
      bk   &= ~m;
    }

    if (lane == 0) keepw_g[k] = bk;

    // ---- append kept rows (single wave: no race) ----
    if ((bk >> lane) & 1ull) {
      int pos = nkept + (int)__popcll(bk & ((1ull << lane) - 1ull));
      kept_off[pos] = (uint32_t)((k * 64 + lane) * Wp * 8);
    }
    nkept += (int)__popcll(bk);
    dw = dwn;
  }
}

// Kernel D: parallel emit.
__global__ __launch_bounds__(256) void k_out(const float* __restrict__ scores_s,
                                             const float4* __restrict__ boxes_s,
                                             const unsigned long long* __restrict__ keepw,
                                             const unsigned* __restrict__ nvp,
                                             float* __restrict__ out) {
  const int r = blockIdx.x * 256 + threadIdx.x;
  if (r >= N_ANCH) return;
  const int nv = (int)*nvp;
  bool kept = false;
  if (r < nv) kept = (keepw[r >> 6] >> (r & 63)) & 1ull;
  float4 b = kept ? boxes_s[r] : make_float4(0.f, 0.f, 0.f, 0.f);
  float s = kept ? scores_s[r] : 0.0f;
  out[r * 5 + 0] = b.x;
  out[r * 5 + 1] = b.y;
  out[r * 5 + 2] = b.z;
  out[r * 5 + 3] = b.w;
  out[r * 5 + 4] = s;
}

extern "C" void kernel_launch(void* const* d_in, const int* in_sizes, int n_in,
                              void* d_out, int out_size, void* d_ws, size_t ws_size,
                              hipStream_t stream) {
  const float* in = (const float*)d_in[0];
  float* out = (float*)d_out;
  uint8_t* ws = (uint8_t*)d_ws;
  unsigned* nvp = (unsigned*)ws;                                       // 64 B
  float* scores_s = (float*)(ws + 64);                                 // 33600 B
  float4* boxes_s = (float4*)(ws + 64 + 33600);                        // NB*16 = 135168 B
  unsigned long long* keepw = (unsigned long long*)(ws + 64 + 33600 + (size_t)NB * 16);  // WMAX*8
  unsigned long long* sup = (unsigned long long*)(ws + 64 + 33600 + (size_t)NB * 16 + 4096);

  (void)hipMemsetAsync(ws, 0, 64, stream);
  k_rank<<<dim3(WMAX), dim3(256), 0, stream>>>(in, scores_s, boxes_s, nvp);
  k_sup<<<dim3(WMAX, (N_ANCH + 255) / 256), dim3(256), 0, stream>>>(boxes_s, nvp, sup);
  k_scan<<<dim3(1), dim3(64), 0, stream>>>(sup, nvp, keepw);
  k_out<<<dim3((N_ANCH + 255) / 256), dim3(256), 0, stream>>>(scores_s, boxes_s, keepw, nvp, out);
}

// Round 12
// 312.554 us; speedup vs baseline: 1.1273x; 1.1273x over previous
//
#include <hip/hip_runtime.h>
#include <cstdint>

#define N_ANCH 8400
#define WMAX   132          // ceil(8400/64)
#define NB     (WMAX * 64)  // padded box slots: 8448
#define NT     512          // k_scan threads: wave0 scans, all 8 waves emit

__device__ __forceinline__ uint64_t readlane64(uint64_t v, int lane) {
  unsigned lo = (unsigned)__builtin_amdgcn_readlane((int)(unsigned)(v & 0xffffffffull), lane);
  unsigned hi = (unsigned)__builtin_amdgcn_readlane((int)(unsigned)(v >> 32), lane);
  return ((uint64_t)hi << 32) | lo;
}
__device__ __forceinline__ uint64_t shflxor64(uint64_t v, int m) {
  int lo = __shfl_xor((int)(unsigned)(v & 0xffffffffull), m, 64);
  int hi = __shfl_xor((int)(unsigned)(v >> 32), m, 64);
  return ((uint64_t)(unsigned)hi << 32) | (unsigned)lo;
}

// Kernel A: exact stable rank (descending score, invalid -> -inf, ties by index),
// scatter boxes/scores into sorted order, count valid. (verified)
__global__ __launch_bounds__(256) void k_rank(const float* __restrict__ in,
                                              float* __restrict__ scores_s,
                                              float4* __restrict__ boxes_s,
                                              unsigned* __restrict__ nvp) {
  __shared__ alignas(16) float sc[N_ANCH];
  __shared__ int part[256];
  const int tid = threadIdx.x;
  const float* srow = in + 4 * N_ANCH;
  for (int j = tid; j < N_ANCH; j += 256) sc[j] = srow[j];
  __syncthreads();
  const int il = tid & 63, q = tid >> 6;
  const int i = blockIdx.x * 64 + il;
  const float si = (i < N_ANCH) ? sc[i] : 0.0f;
  const bool valid = si > 0.5f;
  const float key = valid ? si : -INFINITY;
  int cnt = 0;
  const float4* sc4 = (const float4*)sc;
  const int jb = q * (N_ANCH / 4);
  for (int jj = 0; jj < (N_ANCH / 16); ++jj) {
    float4 v = sc4[q * (N_ANCH / 16) + jj];
    int j0 = jb + jj * 4;
    float k0 = (v.x > 0.5f) ? v.x : -INFINITY;
    float k1 = (v.y > 0.5f) ? v.y : -INFINITY;
    float k2 = (v.z > 0.5f) ? v.z : -INFINITY;
    float k3 = (v.w > 0.5f) ? v.w : -INFINITY;
    cnt += (k0 > key) || (k0 == key && (j0 + 0) < i);
    cnt += (k1 > key) || (k1 == key && (j0 + 1) < i);
    cnt += (k2 > key) || (k2 == key && (j0 + 2) < i);
    cnt += (k3 > key) || (k3 == key && (j0 + 3) < i);
  }
  part[tid] = cnt;
  __syncthreads();
  if (q == 0 && i < N_ANCH) {
    int r = part[il] + part[64 + il] + part[128 + il] + part[192 + il];
    float cx = in[0 * N_ANCH + i], cy = in[1 * N_ANCH + i];
    float w  = in[2 * N_ANCH + i], h  = in[3 * N_ANCH + i];
    float x1 = cx - w * 0.5f, y1 = cy - h * 0.5f;
    float x2 = cx + w * 0.5f, y2 = cy + h * 0.5f;
    boxes_s[r] = make_float4(x1, y1, x2, y2);
    scores_s[r] = valid ? si : 0.0f;
    if (valid) atomicAdd(nvp, 1u);
  }
}

// Kernel B: sup matrix, row-major, stride Wp = (W+3)&~3, UPPER TRIANGLE ONLY
// (w >= rowblock; scan never reads below-diagonal words). Exact IoU path.
__global__ __launch_bounds__(256) void k_sup(const float4* __restrict__ boxes_s,
                                             const unsigned* __restrict__ nvp,
                                             unsigned long long* __restrict__ sup) {
  const int nv = (int)*nvp;
  const int W = (nv + 63) >> 6;
  const int Wp = (W + 3) & ~3;
  const int w = blockIdx.x;
  if (w >= W) return;
  if (w + 1 < (int)(blockIdx.y * 256) >> 6) return;   // whole block in lower triangle
  __shared__ float bx1[64], by1[64], bx2[64], by2[64], bar[64];
  const int tid = threadIdx.x;
  if (tid < 64) {
    int j = w * 64 + tid;
    float4 b = (j < N_ANCH) ? boxes_s[j] : make_float4(0.f, 0.f, 0.f, 0.f);
    bx1[tid] = b.x; by1[tid] = b.y; bx2[tid] = b.z; by2[tid] = b.w;
    bar[tid] = (b.z - b.x) * (b.w - b.y);
  }
  __syncthreads();
  const int i = blockIdx.y * 256 + tid;
  if (i >= nv) return;
  if (w < (i >> 6)) return;                            // lower triangle: never read
  float4 bi = boxes_s[i];
  float ai = (bi.z - bi.x) * (bi.w - bi.y);
  const int jmax = nv - w * 64;
  uint64_t bits = 0;
  #pragma unroll 8
  for (int l = 0; l < 64; ++l) {
    float lx = fmaxf(bi.x, bx1[l]);
    float ly = fmaxf(bi.y, by1[l]);
    float rx = fminf(bi.z, bx2[l]);
    float ry = fminf(bi.w, by2[l]);
    float dx = fmaxf(rx - lx, 0.0f);
    float dy = fmaxf(ry - ly, 0.0f);
    float inter = dx * dy;
    asm volatile("" : "+v"(inter));           // block fma-contraction into union
    float uni = (ai + bar[l]) - inter;        // reference op order
    float iou = inter / uni;                  // IEEE f32 div, matches numpy
    bits |= ((uint64_t)((l < jmax) && (iou > 0.5f))) << l;
  }
  sup[(size_t)i * Wp + w] = bits;
}

// Kernel C: single-wave lazy scan, software-pipelined one full iteration.
// Word-k external suppression = OR over kept rows of sup[row][k]:
//   - rows kept through iter k-1: 8 unrolled clamped batches (h0..h7), issued
//     at the TOP of iter k-1 (one counted vmcnt wait, ~1300cy cover);
//     idle lanes clamp to the last kept row (OR-idempotent, no masks).
//   - rows added at iter k-1: readlane chain over prefetched nwc vector
//     (sup[block k-1 row][k]) — zero memory on the dependent path.
// Diag word prefetched 1 iter ahead. Waves 1-7 only emit at the end.
__global__ __launch_bounds__(NT, 1) void k_scan(const float* __restrict__ scores_s,
                                                const float4* __restrict__ boxes_s,
                                                const unsigned long long* __restrict__ sup_,
                                                const unsigned* __restrict__ nvp,
                                                float* __restrict__ out) {
  __shared__ uint64_t keep_s[WMAX];
  __shared__ uint32_t kept_off[NB];   // byte offsets: row * Wp * 8
  const uint64_t* sup = (const uint64_t*)sup_;
  const uint8_t* supb = (const uint8_t*)sup_;
  const int tid = threadIdx.x;
  const int lane = tid & 63;
  const int wave = tid >> 6;
  const int nv = (int)*nvp;
  const int W  = (nv + 63) >> 6;
  const int Wp = (W + 3) & ~3;

  for (int i = tid; i < WMAX; i += NT) keep_s[i] = 0;
  for (int i = tid; i < 640; i += NT) kept_off[i] = 0;   // clamp targets
  __syncthreads();

  if (wave == 0 && W > 0) {
    uint64_t dw  = sup[(size_t)lane * Wp];                       // diag, block 0
    uint64_t nwc = (W > 1) ? sup[(size_t)lane * Wp + 1] : 0ull;  // block 0, word 1
    uint64_t g0 = 0, g1 = 0, g2 = 0, g3 = 0, g4 = 0, g5 = 0, g6 = 0, g7 = 0;
    uint64_t ncPrev = 0;
    int nkept = 0;

    for (int k = 0; k < W; ++k) {
      // ---- A: issue all prefetches for iteration k+1 ----
      uint64_t dwn = 0, nwn = 0;
      if (k + 1 < W) {
        dwn = sup[((size_t)(k + 1) * 64 + lane) * Wp + (k + 1)];
        if (k + 2 < W) nwn = sup[((size_t)(k + 1) * 64 + lane) * Wp + (k + 2)];
      }
      uint64_t h0 = 0, h1 = 0, h2 = 0, h3 = 0, h4 = 0, h5 = 0, h6 = 0, h7 = 0;
      const int nkNow = nkept;
      if (k + 1 < W && nkNow > 0) {
        const int cl = nkNow - 1;
        const size_t k8n = (size_t)(k + 1) * 8;
        int j;
        j = (lane       < nkNow) ? lane       : cl; h0 = *(const uint64_t*)(supb + kept_off[j] + k8n);
        j = (lane + 64  < nkNow) ? lane + 64  : cl; h1 = *(const uint64_t*)(supb + kept_off[j] + k8n);
        j = (lane + 128 < nkNow) ? lane + 128 : cl; h2 = *(const uint64_t*)(supb + kept_off[j] + k8n);
        j = (lane + 192 < nkNow) ? lane + 192 : cl; h3 = *(const uint64_t*)(supb + kept_off[j] + k8n);
        j = (lane + 256 < nkNow) ? lane + 256 : cl; h4 = *(const uint64_t*)(supb + kept_off[j] + k8n);
        j = (lane + 320 < nkNow) ? lane + 320 : cl; h5 = *(const uint64_t*)(supb + kept_off[j] + k8n);
        j = (lane + 384 < nkNow) ? lane + 384 : cl; h6 = *(const uint64_t*)(supb + kept_off[j] + k8n);
        j = (lane + 448 < nkNow) ? lane + 448 : cl; h7 = *(const uint64_t*)(supb + kept_off[j] + k8n);
        if (nkNow > 512) {              // correctness fallback; never taken here
          for (int t = 512 + lane; t < nkNow; t += 64)
            h7 |= *(const uint64_t*)(supb + kept_off[t] + k8n);
        }
      }

      // ---- B: finish word-k accumulation (previous iteration's loads) ----
      uint64_t acc = g0 | g1 | g2 | g3 | g4 | g5 | g6 | g7;
      acc |= shflxor64(acc, 1);  acc |= shflxor64(acc, 2);  acc |= shflxor64(acc, 4);
      acc |= shflxor64(acc, 8);  acc |= shflxor64(acc, 16); acc |= shflxor64(acc, 32);
      acc |= ncPrev;

      // ---- C: candidates + serial diag resolve (proven chain) ----
      const int remv = nv - k * 64;
      uint64_t word = (remv >= 64) ? ~0ull : ((1ull << remv) - 1ull);
      uint64_t bk = word & ~acc;
      uint64_t cand = bk;
      while (cand) {
        int r = (int)__builtin_ctzll(cand);
        uint64_t sr = readlane64(dw, r);
        uint64_t m = sr & ~((2ull << r) - 1ull);   // cols strictly > r
        cand &= ~(1ull << r);
        cand &= ~m;
        bk   &= ~m;
      }
      if (lane == 0) keep_s[k] = bk;

      // ---- D: append kept rows; their word-(k+1) contribution via nwc ----
      if ((bk >> lane) & 1ull) {
        int pos = nkept + (int)__popcll(bk & ((1ull << lane) - 1ull));
        kept_off[pos] = (uint32_t)((uint32_t)(k * 64 + lane) * (uint32_t)Wp * 8u);
      }
      nkept += (int)__popcll(bk);
      uint64_t nc = 0, remA = bk;
      while (remA) {
        int r = (int)__builtin_ctzll(remA);
        remA &= remA - 1;
        nc |= readlane64(nwc, r);
      }

      // ---- E: carry pipeline state ----
      g0 = h0; g1 = h1; g2 = h2; g3 = h3; g4 = h4; g5 = h5; g6 = h6; g7 = h7;
      dw = dwn; nwc = nwn; ncPrev = nc;
    }
  }
  __syncthreads();

  // ---- emit output (all 8 waves) ----
  for (int r = tid; r < N_ANCH; r += NT) {
    bool kept = (r < nv) && ((keep_s[r >> 6] >> (r & 63)) & 1ull);
    float4 b = kept ? boxes_s[r] : make_float4(0.f, 0.f, 0.f, 0.f);
    float s = kept ? scores_s[r] : 0.0f;
    out[r * 5 + 0] = b.x;
    out[r * 5 + 1] = b.y;
    out[r * 5 + 2] = b.z;
    out[r * 5 + 3] = b.w;
    out[r * 5 + 4] = s;
  }
}

extern "C" void kernel_launch(void* const* d_in, const int* in_sizes, int n_in,
                              void* d_out, int out_size, void* d_ws, size_t ws_size,
                              hipStream_t stream) {
  const float* in = (const float*)d_in[0];
  float* out = (float*)d_out;
  uint8_t* ws = (uint8_t*)d_ws;
  unsigned* nvp = (unsigned*)ws;                                       // 64 B
  float* scores_s = (float*)(ws + 64);                                 // 33600 B
  float4* boxes_s = (float4*)(ws + 64 + 33600);                        // NB*16 = 135168 B
  unsigned long long* sup = (unsigned long long*)(ws + 64 + 33600 + (size_t)NB * 16);  // NB*Wp*8

  (void)hipMemsetAsync(ws, 0, 64, stream);
  k_rank<<<dim3(WMAX), dim3(256), 0, stream>>>(in, scores_s, boxes_s, nvp);
  k_sup<<<dim3(WMAX, (N_ANCH + 255) / 256), dim3(256), 0, stream>>>(boxes_s, nvp, sup);
  k_scan<<<dim3(1), dim3(NT), 0, stream>>>(scores_s, boxes_s, sup, nvp, out);
}